// Round 5
// baseline (274.405 us; speedup 1.0000x reference)
//
#include <hip/hip_runtime.h>

typedef __bf16 bf16x8 __attribute__((ext_vector_type(8)));
typedef float f32x4 __attribute__((ext_vector_type(4)));

#define MFMA(a,b,c) __builtin_amdgcn_mfma_f32_16x16x32_bf16((a),(b),(c),0,0,0)

__device__ __forceinline__ float rcp_(float x){ return __builtin_amdgcn_rcpf(x); }

#define L2E 1.4426950408889634f
#define LN2 0.6931471805599453f

// ---------------- prep: fold weights, build per-tid B-frag table -------------
// Per main-kernel tid (0..511): 14 bf16x8 frags (224 B) + 4 f32 (16 B) = 240 B.
//  f0,f1 : G1 T0 (cols = gates i/f x 8 hid)  G1 = L2E*(Whh @ Wh_p)
//  f2,f3 : G1 T1 (cols = gates g/o; g x2)
//  f4,f5 : G2 T0                             G2 = L2E*(Whh @ Wh_u)
//  f6,f7 : G2 T1
//  f8..11: c-tile (cols = Wh2 row hcol, duplicated across l16>>3), K=128 [p|u]
//  f12,13: fc diff (Wfc[0]-Wfc[1] broadcast over cols), K=64
//  scalars: baseT0,dvecT0,baseT1,dvecT1 (pre-scaled by L2E, g-gate x2)
__global__ __launch_bounds__(256) void prep_kernel(
    const float* __restrict__ Wh,  const float* __restrict__ Wh2,
    const float* __restrict__ Whh, const float* __restrict__ Wfc,
    const float* __restrict__ Wih, const float* __restrict__ bih,
    const float* __restrict__ bhh,
    char* __restrict__ tblc)
{
  const int idx = blockIdx.x*256 + threadIdx.x;
  if (idx < 512*14*8){
    const int e = idx & 7, f = (idx >> 3) % 14, t = (idx >> 3) / 14;
    const int w = t >> 6, lane = t & 63, l16 = lane & 15;
    const int g8 = ((lane >> 4) & 3) * 8;
    const int hcol = w*8 + (l16 & 7), hi = l16 >> 3;
    float val;
    if (f < 8){
      const int half = (f >> 2) & 1;          // 0: Wh_p, 1: Wh_u
      const int tile = (f >> 1) & 1;          // 0: T0(i/f), 1: T1(g/o)
      const int s    = f & 1;
      const int gate = tile*2 + hi;
      const int n = gate*64 + hcol;
      const int k = s*32 + g8 + e;
      float acc = 0.f;
      for (int j=0; j<64; ++j) acc += Whh[n*64 + j] * Wh[j*128 + half*64 + k];
      val = acc * ((gate == 2) ? 2.f*L2E : L2E);
    } else if (f < 12){
      const int s = f - 8;
      const int k = (s & 1)*32 + g8 + e;
      val = Wh2[hcol*128 + (s >> 1)*64 + k];
    } else {
      const int k = (f & 1)*32 + g8 + e;
      val = Wfc[k] - Wfc[64 + k];
    }
    *(__bf16*)(tblc + t*240 + f*16 + e*2) = (__bf16)val;
  } else if (idx < 512*14*8 + 512*4){
    const int j = idx - 512*14*8;
    const int t = j >> 2, q = j & 3;
    const int w = t >> 6, lane = t & 63, l16 = lane & 15, hi = l16 >> 3;
    const int tile = q >> 1, kind = q & 1;
    const int gate = tile*2 + hi;
    const int n = gate*64 + w*8 + (l16 & 7);
    const float sc = (gate == 2) ? 2.f*L2E : L2E;
    const float v = kind ? sc*(Wih[n*2] - Wih[n*2+1])
                         : sc*(bih[n] + bhh[n] + Wih[n*2+1]);
    *(float*)(tblc + t*240 + 224 + q*4) = v;
  }
}

// ---------------- main: 256 blocks x 512 threads (8 waves, 16 samples) ------
// Wave w owns hidden cols [8w, 8w+8): all 4 gates via 2 permuted N-tiles +
// its c_inter slice (duplicated-col tile). K = full hidden (shared across
// waves). One barrier/cell. Epilogue: 2 els/lane after 4x shfl_xor(8) gate
// exchange. Softmax deferred: wave0's fc-tile parks d(slot) in s_d; one
// parallel end-phase does all 4096 log1p terms + popcount aa + rec fix.
__global__ __launch_bounds__(512,2) void lstm2d_kernel(
    const float* __restrict__ x,   const float* __restrict__ Wx,
    const float* __restrict__ bfc,
    const char* __restrict__ tblc,
    float* __restrict__ out)
{
  __shared__ __align__(16) __bf16 s_h[16*16*64];   // [col][row][hid] 32 KB
  __shared__ __align__(16) __bf16 s_c[16*16*64];   // 32 KB
  __shared__ __align__(16) float  s_xh[256*16];    // [slot][row] 16 KB
  __shared__ __align__(16) float  s_d[256*16];     // [slot][row] 16 KB
  __shared__ unsigned int s_msk[16*8];
  __shared__ float s_red[8*16];

  const int tid  = threadIdx.x;
  const int w    = tid >> 6;
  const int lane = tid & 63;
  const int l16  = lane & 15;
  const int g4   = lane >> 4;
  const int g8   = g4 * 8;
  const int hi   = l16 >> 3;
  const bool lo  = (hi == 0);

  const float wx0 = Wx[0], wx1 = Wx[1];
  const float bd  = bfc[0] - bfc[1];

  // zero h/c
  unsigned int* zh = (unsigned int*)s_h;
  unsigned int* zc = (unsigned int*)s_c;
  #pragma unroll
  for (int it=0; it<16; ++it){ zh[tid + it*512] = 0u; zc[tid + it*512] = 0u; }

  // xh precompute
  const float* xg = x + blockIdx.x * 4096;
  #pragma unroll
  for (int k=0; k<8; ++k){
    const int idx = tid + k*512;
    const int row = idx & 15, slot = idx >> 4;
    const int i = slot >> 4, t = slot & 15;
    const int c   = (i & 1) ? 15 - t : t;
    const int cpc = (i & 1) ? c + 1 : c - 1;
    const float xp = (t > 0) ? xg[row*256 + i*16 + cpc] : 0.f;
    const float xu = (i > 0) ? xg[row*256 + (i-1)*16 + c] : 0.f;
    s_xh[slot*16 + row] = (xp*wx0 + xu*wx1 + 1.f) * 0.5f;
  }
  // mask bits
  if (tid < 128){
    const int row = tid >> 3, wd = tid & 7;
    unsigned int m = 0;
    for (int b=0; b<32; ++b){
      const int slot = wd*32 + b, i = slot >> 4, t = slot & 15;
      const int c = (i & 1) ? 15 - t : t;
      if (xg[row*256 + i*16 + c] > 0.f) m |= (1u << b);
    }
    s_msk[row*8 + wd] = m;
  }

  // weight fragments
  const char* tb = tblc + tid*240;
  bf16x8 g1T0[2], g1T1[2], g2T0[2], g2T1[2], cB[4], fcB[2];
  g1T0[0] = *(const bf16x8*)(tb +   0); g1T0[1] = *(const bf16x8*)(tb +  16);
  g1T1[0] = *(const bf16x8*)(tb +  32); g1T1[1] = *(const bf16x8*)(tb +  48);
  g2T0[0] = *(const bf16x8*)(tb +  64); g2T0[1] = *(const bf16x8*)(tb +  80);
  g2T1[0] = *(const bf16x8*)(tb +  96); g2T1[1] = *(const bf16x8*)(tb + 112);
  #pragma unroll
  for (int s=0; s<4; ++s) cB[s] = *(const bf16x8*)(tb + 128 + s*16);
  fcB[0] = *(const bf16x8*)(tb + 192); fcB[1] = *(const bf16x8*)(tb + 208);
  const float base0 = *(const float*)(tb + 224);
  const float dvec0 = *(const float*)(tb + 228);
  const float base1 = *(const float*)(tb + 232);
  const float dvec1 = *(const float*)(tb + 236);

  // per-lane LDS offsets (elements)
  const int offA0 = l16*64 + ((     g8) ^ ((l16 & 7) << 3));
  const int offA1 = l16*64 + ((32 + g8) ^ ((l16 & 7) << 3));
  const int habs = w*8 + (l16 & 7);
  int stWa[2];
  #pragma unroll
  for (int e=0; e<2; ++e){
    const int R = g4*4 + 2*hi + e;
    stWa[e] = R*64 + (habs ^ ((R & 7) << 3));
  }
  const float C2 = -2.f*L2E;

  __syncthreads();

  f32x4 aT0u, aT1u, aCu;

  for (int i=0; i<16; ++i){
    const int dir = i & 1;
    const int slot0 = i*16;

    // ---- prologue: up contributions for t=0; d(prev row's last slot) ----
    {
      const int bu = (dir ? 15 : 0) << 10;
      bf16x8 h0 = *(const bf16x8*)(s_h + bu + offA0);
      bf16x8 h1 = *(const bf16x8*)(s_h + bu + offA1);
      bf16x8 c0 = *(const bf16x8*)(s_c + bu + offA0);
      bf16x8 c1 = *(const bf16x8*)(s_c + bu + offA1);
      const float4 xh4 = *(const float4*)(s_xh + slot0*16 + g4*4);
      #pragma unroll
      for (int r=0;r<4;++r){
        const float xh = (&xh4.x)[r];
        aT0u[r] = base0 + xh*dvec0;
        aT1u[r] = base1 + xh*dvec1;
      }
      aT0u = MFMA(h0, g2T0[0], aT0u); aT0u = MFMA(h1, g2T0[1], aT0u);
      aT1u = MFMA(h0, g2T1[0], aT1u); aT1u = MFMA(h1, g2T1[1], aT1u);
      f32x4 z = {0.f,0.f,0.f,0.f};
      aCu = MFMA(c0, cB[2], z); aCu = MFMA(c1, cB[3], aCu);
      if (w == 0 && i > 0){
        f32x4 fz = {bd,bd,bd,bd};
        fz = MFMA(h0, fcB[0], fz);
        f32x4 aF = MFMA(h1, fcB[1], fz);
        if (l16 == 0){
          #pragma unroll
          for (int r=0;r<4;++r) s_d[(slot0-1)*16 + g4*4 + r] = aF[r];
        }
      }
    }

    for (int t=0; t<16; ++t){
      const int c    = dir ? 15 - t : t;
      const int slot = slot0 + t;

      // ---------- phase 1: gates + c_inter (+ wave0: d(slot-1)) ----------
      f32x4 aT0 = aT0u, aT1 = aT1u, aC = aCu;
      if (t > 0){
        const int bp = (dir ? c + 1 : c - 1) << 10;
        bf16x8 a0 = *(const bf16x8*)(s_h + bp + offA0);
        bf16x8 a1 = *(const bf16x8*)(s_h + bp + offA1);
        bf16x8 q0 = *(const bf16x8*)(s_c + bp + offA0);
        bf16x8 q1 = *(const bf16x8*)(s_c + bp + offA1);
        aT0 = MFMA(a0, g1T0[0], aT0); aT0 = MFMA(a1, g1T0[1], aT0);
        aT1 = MFMA(a0, g1T1[0], aT1); aT1 = MFMA(a1, g1T1[1], aT1);
        aC  = MFMA(q0, cB[0], aC);    aC  = MFMA(q1, cB[1], aC);
        if (w == 0){
          f32x4 fz = {bd,bd,bd,bd};
          fz = MFMA(a0, fcB[0], fz);
          f32x4 aF = MFMA(a1, fcB[1], fz);
          if (l16 == 0){
            #pragma unroll
            for (int r=0;r<4;++r) s_d[(slot-1)*16 + g4*4 + r] = aF[r];
          }
        }
      }

      // ---------- prefetch next slot's up contribution ----------
      if (t < 15){
        const int bu = (dir ? 14 - t : t + 1) << 10;
        bf16x8 h0 = *(const bf16x8*)(s_h + bu + offA0);
        bf16x8 h1 = *(const bf16x8*)(s_h + bu + offA1);
        bf16x8 c0 = *(const bf16x8*)(s_c + bu + offA0);
        bf16x8 c1 = *(const bf16x8*)(s_c + bu + offA1);
        const float4 xh4 = *(const float4*)(s_xh + (slot+1)*16 + g4*4);
        #pragma unroll
        for (int r=0;r<4;++r){
          const float xh = (&xh4.x)[r];
          aT0u[r] = base0 + xh*dvec0;
          aT1u[r] = base1 + xh*dvec1;
        }
        aT0u = MFMA(h0, g2T0[0], aT0u); aT0u = MFMA(h1, g2T0[1], aT0u);
        aT1u = MFMA(h0, g2T1[0], aT1u); aT1u = MFMA(h1, g2T1[1], aT1u);
        f32x4 z = {0.f,0.f,0.f,0.f};
        aCu = MFMA(c0, cB[2], z); aCu = MFMA(c1, cB[3], aCu);
      }

      // ---------- epilogue: gate exchange + activations (2 els/lane) ----
      const int cb = c << 10;
      #pragma unroll
      for (int e=0; e<2; ++e){
        const float sendT0 = lo ? aT0[2+e] : aT0[e];
        const float sendT1 = lo ? aT1[2+e] : aT1[e];
        const float rT0 = __shfl_xor(sendT0, 8);
        const float rT1 = __shfl_xor(sendT1, 8);
        const float own0 = lo ? aT0[e] : aT0[2+e];
        const float own1 = lo ? aT1[e] : aT1[2+e];
        const float ig = lo ? own0 : rT0;
        const float fg = lo ? rT0  : own0;
        const float gg = lo ? own1 : rT1;
        const float og = lo ? rT1  : own1;
        const float cI = lo ? aC[e] : aC[2+e];
        const float si = rcp_(1.f + exp2f(-ig));
        const float sf = rcp_(1.f + exp2f(-fg));
        const float tg = 2.f * rcp_(1.f + exp2f(-gg)) - 1.f;
        const float cn = sf*cI + si*tg;
        const float so = rcp_(1.f + exp2f(-og));
        const float tc = 2.f * rcp_(1.f + exp2f(C2*cn)) - 1.f;
        const float hn = so * tc;
        s_h[cb + stWa[e]] = (__bf16)hn;
        s_c[cb + stWa[e]] = (__bf16)cn;
      }

      __syncthreads();
    }
  }

  // d(255): column 0 holds h(255)
  if (w == 0){
    bf16x8 a0 = *(const bf16x8*)(s_h + offA0);
    bf16x8 a1 = *(const bf16x8*)(s_h + offA1);
    f32x4 fz = {bd,bd,bd,bd};
    fz = MFMA(a0, fcB[0], fz);
    f32x4 aF = MFMA(a1, fcB[1], fz);
    if (l16 == 0){
      #pragma unroll
      for (int r=0;r<4;++r) s_d[255*16 + g4*4 + r] = aF[r];
    }
  }
  __syncthreads();

  // ---------- end phase: all 4096 log-softmax terms in parallel ----------
  {
    const int row = tid & 15, grp = tid >> 4;   // grp 0..31, 8 slots each
    float lpp = 0.f;
    #pragma unroll
    for (int e=0; e<8; ++e){
      const int slot = grp*8 + e;
      const float d = s_d[slot*16 + row];
      const int msk = (s_msk[row*8 + (slot >> 5)] >> (slot & 31)) & 1;
      const float zz = msk ? -d : d;
      lpp -= LN2 * log2f(1.f + exp2f(zz * L2E));
    }
    lpp += __shfl_xor(lpp, 16);
    lpp += __shfl_xor(lpp, 32);
    if (lane < 16) s_red[w*16 + lane] = lpp;
  }
  __syncthreads();
  if (tid < 16){
    const int row = tid;
    float lp = 0.f;
    #pragma unroll
    for (int ww=0; ww<8; ++ww) lp += s_red[ww*16 + row];
    int aa = 0;
    #pragma unroll
    for (int wd=0; wd<8; ++wd) aa += __popc(s_msk[row*8 + wd]);
    const int m255 = (s_msk[row*8 + 7] >> 31) & 1;
    if (aa == 1 && m255){
      const float d = s_d[255*16 + row];
      lp += LN2 * log2f(1.f + exp2f(-d * L2E));   // remove contrib (factor=0)
    }
    out[blockIdx.x*16 + row] = lp;
  }
}

extern "C" void kernel_launch(void* const* d_in, const int* in_sizes, int n_in,
                              void* d_out, int out_size, void* d_ws, size_t ws_size,
                              hipStream_t stream) {
  const float* x   = (const float*)d_in[0];
  const float* Wx  = (const float*)d_in[1];
  const float* Wh  = (const float*)d_in[2];
  const float* Wh2 = (const float*)d_in[3];
  const float* Wih = (const float*)d_in[4];
  const float* Whh = (const float*)d_in[5];
  const float* bih = (const float*)d_in[6];
  const float* bhh = (const float*)d_in[7];
  const float* Wfc = (const float*)d_in[8];
  const float* bfc = (const float*)d_in[9];
  float* out = (float*)d_out;
  char* tbl = (char*)d_ws;    // 512*240 = 122880 B

  prep_kernel<<<dim3(((512*14*8 + 512*4) + 255)/256), dim3(256), 0, stream>>>(
      Wh, Wh2, Whh, Wfc, Wih, bih, bhh, tbl);
  lstm2d_kernel<<<dim3(256), dim3(512), 0, stream>>>(x, Wx, bfc, tbl, out);
}